// Round 6
// baseline (726.051 us; speedup 1.0000x reference)
//
#include <hip/hip_runtime.h>
#include <hip/hip_bf16.h>

#define H 1024
#define F 4096
#define NE 8
#define T 4096
// split-K factor for gemm2: K=4096 -> 2 chunks of 2048.
#define KSPLIT2 2

typedef unsigned short u16;
typedef float floatx4 __attribute__((ext_vector_type(4)));
typedef short short8 __attribute__((ext_vector_type(8)));

__device__ __forceinline__ u16 f2bf(float f) {
  union { float f; unsigned int u; } c; c.f = f;
  unsigned int u = c.u;
  return (u16)((u + 0x7fffu + ((u >> 16) & 1u)) >> 16);
}

// async global->LDS, 16B per lane. LDS dest must be uniform base + lane*16.
__device__ __forceinline__ void load16_lds(const u16* g, u16* l) {
  __builtin_amdgcn_global_load_lds(
      (const __attribute__((address_space(1))) unsigned int*)g,
      (__attribute__((address_space(3))) unsigned int*)l, 16, 0, 0);
}

// exact-enough GELU: erf via Abramowitz-Stegun 7.1.26, |err|<1.5e-7.
__device__ __forceinline__ float gelu_f(float v) {
  float y = fabsf(v) * 0.70710678118f;
  float t = __builtin_amdgcn_rcpf(fmaf(0.3275911f, y, 1.0f));
  float p = t * fmaf(t, fmaf(t, fmaf(t, fmaf(t, 1.061405429f, -1.453152027f),
                                     1.421413741f), -0.284496736f), 0.254829592f);
  float e = __builtin_amdgcn_exp2f(-y * y * 1.44269504f);
  float erfv = fmaf(-p, e, 1.0f);
  return fmaf(0.5f * fabsf(v), erfv, 0.5f * v);
}

// ---------------- router: one wave per token, fp64 logits ----------------
__global__ __launch_bounds__(256) void router_kernel(
    const float* __restrict__ x, const float* __restrict__ Wr,
    int* __restrict__ cnt, int* __restrict__ tok, float* __restrict__ wgt) {
  int t = (blockIdx.x * 256 + threadIdx.x) >> 6;
  int lane = threadIdx.x & 63;
  const float* xr = x + (size_t)t * H;
  double p[NE];
#pragma unroll
  for (int e = 0; e < NE; ++e) p[e] = 0.0;
  for (int k = lane; k < H; k += 64) {
    float xv = xr[k];
    const float4* wr4 = reinterpret_cast<const float4*>(Wr + k * NE);
    float4 a = wr4[0], b = wr4[1];
    p[0] += (double)xv * a.x; p[1] += (double)xv * a.y;
    p[2] += (double)xv * a.z; p[3] += (double)xv * a.w;
    p[4] += (double)xv * b.x; p[5] += (double)xv * b.y;
    p[6] += (double)xv * b.z; p[7] += (double)xv * b.w;
  }
#pragma unroll
  for (int e = 0; e < NE; ++e) {
#pragma unroll
    for (int off = 32; off; off >>= 1) p[e] += __shfl_down(p[e], off, 64);
  }
  if (lane == 0) {
    int i0 = 0;
#pragma unroll
    for (int e = 1; e < NE; ++e) if (p[e] > p[i0]) i0 = e;
    int i1 = (i0 == 0) ? 1 : 0;
#pragma unroll
    for (int e = 0; e < NE; ++e) if (e != i0 && p[e] > p[i1]) i1 = e;
    double d = exp(p[i1] - p[i0]);
    float w0 = (float)(1.0 / (1.0 + d));
    float w1 = (float)(d / (1.0 + d));
    int pos0 = atomicAdd(&cnt[i0], 1);
    tok[i0 * T + pos0] = t; wgt[i0 * T + pos0] = w0;
    int pos1 = atomicAdd(&cnt[i1], 1);
    tok[i1 * T + pos1] = t; wgt[i1 * T + pos1] = w1;
  }
}

__global__ void offsets_kernel(const int* __restrict__ cnt, int* __restrict__ off) {
  if (threadIdx.x == 0) {
    int s = 0;
#pragma unroll
    for (int e = 0; e < NE; ++e) { off[e] = s; s += cnt[e]; }
    off[NE] = s;
  }
}

// ---------------- x -> bf16 ----------------
__global__ __launch_bounds__(256) void convert_x_kernel(
    const float* __restrict__ x, u16* __restrict__ xb) {
  int i = blockIdx.x * 256 + threadIdx.x;
  float4 v = reinterpret_cast<const float4*>(x)[i];
  ushort4 o;
  o.x = f2bf(v.x); o.y = f2bf(v.y); o.z = f2bf(v.z); o.w = f2bf(v.w);
  reinterpret_cast<ushort4*>(xb)[i] = o;
}

// ---- fused weight transpose: [E][R][C] f32 -> [E][C][R] bf16, both W1,W2 ----
__global__ __launch_bounds__(256) void transpose_both_kernel(
    const float* __restrict__ W1, const float* __restrict__ W2,
    u16* __restrict__ W1t, u16* __restrict__ W2t) {
  __shared__ u16 tile[64][72];
  int z = blockIdx.z;
  int e = z & 7;
  const float* s; u16* d; int R, C, c0, r0;
  if (z < NE) {
    s = W1 + (size_t)e * H * F; d = W1t + (size_t)e * H * F;
    R = H; C = F; c0 = blockIdx.x << 6; r0 = blockIdx.y << 6;
  } else {
    s = W2 + (size_t)e * F * H; d = W2t + (size_t)e * F * H;
    R = F; C = H; c0 = blockIdx.y << 6; r0 = blockIdx.x << 6;
  }
  int t = threadIdx.x;
  int rl = t >> 4, cl = (t & 15) << 2;
#pragma unroll
  for (int i = 0; i < 4; ++i) {
    float4 v = *reinterpret_cast<const float4*>(&s[(size_t)(r0 + rl + i * 16) * C + c0 + cl]);
    ushort4 o; o.x = f2bf(v.x); o.y = f2bf(v.y); o.z = f2bf(v.z); o.w = f2bf(v.w);
    *reinterpret_cast<ushort4*>(&tile[rl + i * 16][cl]) = o;
  }
  __syncthreads();
  int cl2 = t >> 4, rl2 = (t & 15) << 2;
#pragma unroll
  for (int i = 0; i < 4; ++i) {
    ushort4 o;
    o.x = tile[rl2 + 0][cl2 + i * 16];
    o.y = tile[rl2 + 1][cl2 + i * 16];
    o.z = tile[rl2 + 2][cl2 + i * 16];
    o.w = tile[rl2 + 3][cl2 + i * 16];
    *reinterpret_cast<ushort4*>(&d[(size_t)(c0 + cl2 + i * 16) * R + r0 + rl2]) = o;
  }
}

// ============ 256x256 tile, BK=64, 512 thr (8 waves 2Mx4N) GEMMs ============
// Verified loop logic from round 4, scaled: 2 LDS buffers, depth-2 counted
// vmcnt(8), stage-after-second-barrier. BK=64 swizzle: phys 16B chunk p of row
// r holds logical k-chunk p^(r&7); staging pre-swizzles the GLOBAL source so
// the LDS dest stays linear (global_load_lds requirement); reads apply the
// same XOR -> 16-lane groups hit all 8 chunk-slots (2-way = free).
// 1 block/CU (128KB LDS); acc[8][4] = per-wave 128x64 output.

// ---------------- GEMM1: Hc = gelu(gather(Xb) @ W1t^T + b1) ----------------
// grid 768: e = bid&7 (XCD affinity), rem = bid>>3: by = rem%6 (m fastest), bx = rem/6.
__global__ __launch_bounds__(512, 2) void gemm1_kernel(
    const u16* __restrict__ Xb, const u16* __restrict__ W1t,
    const float* __restrict__ b1, const int* __restrict__ cnt,
    const int* __restrict__ off, const int* __restrict__ tok,
    u16* __restrict__ Hc) {
  int bid = blockIdx.x;
  int e = bid & 7;
  int rem = bid >> 3;
  int by = rem % 6;
  int bx = rem / 6;            // 0..15
  int n = cnt[e];
  int m0 = by << 8;
  if (m0 >= n) return;
  int n0 = bx << 8;
  int rb = off[e];

  __shared__ alignas(16) u16 As[2][256 * 64];
  __shared__ alignas(16) u16 Bs[2][256 * 64];
  __shared__ int tokS[256];

  int tid = threadIdx.x;
  if (tid < 256) {
    int s = m0 + tid;
    tokS[tid] = (s < n) ? tok[e * T + s] : 0;
  }
  __syncthreads();

  // staging: 4 chunks/thread each for A,B: g = tid + s*512; row r=g>>3, slot
  // p=g&7; source k-chunk = p ^ (r&7) (pre-swizzled global address).
  const u16* W1e = W1t + (size_t)e * F * H;
  const u16* aP[4]; const u16* bP[4];
#pragma unroll
  for (int s = 0; s < 4; ++s) {
    int g = tid + s * 512;
    int r = g >> 3, p = g & 7;
    int kcc = (p ^ (r & 7)) * 8;
    aP[s] = Xb + (size_t)tokS[r] * H + kcc;
    bP[s] = W1e + (size_t)(n0 + r) * H + kcc;
  }

  int wv = tid >> 6, lane = tid & 63;
  int wm = wv >> 2, wn = wv & 3;
  int quad = lane >> 4, l16 = lane & 15;

  floatx4 acc[8][4];
#pragma unroll
  for (int mt = 0; mt < 8; ++mt)
#pragma unroll
    for (int nt = 0; nt < 4; ++nt) acc[mt][nt] = floatx4{0.f, 0.f, 0.f, 0.f};

  // read offsets (u16 idx): row*64 + ((kk*4+quad)^(l16&7))*8
  int xq[2];
#pragma unroll
  for (int kk = 0; kk < 2; ++kk) xq[kk] = ((kk * 4 + quad) ^ (l16 & 7)) * 8;
  int aRow[8], bRow[4];
#pragma unroll
  for (int mt = 0; mt < 8; ++mt) aRow[mt] = (wm * 128 + mt * 16 + l16) * 64;
#pragma unroll
  for (int nt = 0; nt < 4; ++nt) bRow[nt] = (wn * 64 + nt * 16 + l16) * 64;

#define STAGE1(buf, kk0)                                          \
  do {                                                            \
    _Pragma("unroll")                                             \
    for (int s = 0; s < 4; ++s) {                                 \
      load16_lds(aP[s] + (kk0), &As[buf][(tid + s * 512) * 8]);   \
      load16_lds(bP[s] + (kk0), &Bs[buf][(tid + s * 512) * 8]);   \
    }                                                             \
  } while (0)

  const int NIT = H / 64;  // 16
  STAGE1(0, 0);
  STAGE1(1, 64);
  for (int it = 0; it < NIT; ++it) {
    if (it >= NIT - 1) asm volatile("s_waitcnt vmcnt(0)" ::: "memory");
    else               asm volatile("s_waitcnt vmcnt(8)" ::: "memory");
    __builtin_amdgcn_s_barrier();
    int cur = it & 1;
#pragma unroll
    for (int kk = 0; kk < 2; ++kk) {
      short8 bv[4];
#pragma unroll
      for (int nt = 0; nt < 4; ++nt)
        bv[nt] = *reinterpret_cast<const short8*>(&Bs[cur][bRow[nt] + xq[kk]]);
#pragma unroll
      for (int mt = 0; mt < 8; ++mt) {
        short8 av = *reinterpret_cast<const short8*>(&As[cur][aRow[mt] + xq[kk]]);
#pragma unroll
        for (int nt = 0; nt < 4; ++nt)
          acc[mt][nt] = __builtin_amdgcn_mfma_f32_16x16x32_bf16(av, bv[nt], acc[mt][nt], 0, 0, 0);
      }
    }
    __builtin_amdgcn_s_barrier();  // all waves done reading buf cur
    if (it + 2 < NIT) STAGE1(cur, (it + 2) * 64);
  }
#undef STAGE1

  // epilogue: bias + gelu -> bf16 -> Hc[rb + row][col]
  float b1v[4];
#pragma unroll
  for (int nt = 0; nt < 4; ++nt)
    b1v[nt] = b1[e * F + n0 + wn * 64 + nt * 16 + l16];
#pragma unroll
  for (int mt = 0; mt < 8; ++mt) {
#pragma unroll
    for (int i = 0; i < 4; ++i) {
      int row = wm * 128 + mt * 16 + quad * 4 + i;
      int gr = m0 + row;
      if (gr < n) {
        u16* hrow = Hc + (size_t)(rb + gr) * F + n0 + wn * 64 + l16;
#pragma unroll
        for (int nt = 0; nt < 4; ++nt) {
          float v = acc[mt][nt][i] + b1v[nt];
          hrow[nt * 16] = f2bf(gelu_f(v));
        }
      }
    }
  }
}

// ---------------- GEMM2: out += w * (Hc @ W2t^T + b2) ----------------
// grid 384: e = bid&7; rem = bid>>3: by = rem%6 (m fastest), rem2 = rem/6:
// kc = rem2&1, bx = rem2>>1 (0..3). fp32 atomic epilogue; b2 on kc==0.
__global__ __launch_bounds__(512, 2) void gemm2_kernel(
    const u16* __restrict__ Hc, const u16* __restrict__ W2t,
    const float* __restrict__ b2, const int* __restrict__ cnt,
    const int* __restrict__ off, const int* __restrict__ tok,
    const float* __restrict__ wgt, float* __restrict__ out) {
  int bid = blockIdx.x;
  int e = bid & 7;
  int rem = bid >> 3;
  int by = rem % 6;
  int rem2 = rem / 6;
  int kc = rem2 & 1;
  int bx = rem2 >> 1;          // 0..3
  int n = cnt[e];
  int m0 = by << 8;
  if (m0 >= n) return;
  int n0 = bx << 8;
  int rb = off[e];

  __shared__ alignas(16) u16 As[2][256 * 64];
  __shared__ alignas(16) u16 Bs[2][256 * 64];

  int tid = threadIdx.x;
  const u16* W2e = W2t + (size_t)e * F * H;
  const u16* aP[4]; const u16* bP[4];
#pragma unroll
  for (int s = 0; s < 4; ++s) {
    int g = tid + s * 512;
    int r = g >> 3, p = g & 7;
    int kcc = (p ^ (r & 7)) * 8;
    int r2 = m0 + r; if (r2 > n - 1) r2 = n - 1;  // clamp: stay in expert's Hc rows
    aP[s] = Hc + (size_t)(rb + r2) * F + kcc;
    bP[s] = W2e + (size_t)(n0 + r) * F + kcc;
  }

  int wv = tid >> 6, lane = tid & 63;
  int wm = wv >> 2, wn = wv & 3;
  int quad = lane >> 4, l16 = lane & 15;

  floatx4 acc[8][4];
#pragma unroll
  for (int mt = 0; mt < 8; ++mt)
#pragma unroll
    for (int nt = 0; nt < 4; ++nt) acc[mt][nt] = floatx4{0.f, 0.f, 0.f, 0.f};

  int xq[2];
#pragma unroll
  for (int kk = 0; kk < 2; ++kk) xq[kk] = ((kk * 4 + quad) ^ (l16 & 7)) * 8;
  int aRow[8], bRow[4];
#pragma unroll
  for (int mt = 0; mt < 8; ++mt) aRow[mt] = (wm * 128 + mt * 16 + l16) * 64;
#pragma unroll
  for (int nt = 0; nt < 4; ++nt) bRow[nt] = (wn * 64 + nt * 16 + l16) * 64;

#define STAGE2(buf, kk0)                                          \
  do {                                                            \
    _Pragma("unroll")                                             \
    for (int s = 0; s < 4; ++s) {                                 \
      load16_lds(aP[s] + (kk0), &As[buf][(tid + s * 512) * 8]);   \
      load16_lds(bP[s] + (kk0), &Bs[buf][(tid + s * 512) * 8]);   \
    }                                                             \
  } while (0)

  const int kBeg = kc * (F / KSPLIT2);
  const int NIT = (F / KSPLIT2) / 64;  // 32
  STAGE2(0, kBeg);
  STAGE2(1, kBeg + 64);
  for (int it = 0; it < NIT; ++it) {
    if (it >= NIT - 1) asm volatile("s_waitcnt vmcnt(0)" ::: "memory");
    else               asm volatile("s_waitcnt vmcnt(8)" ::: "memory");
    __builtin_amdgcn_s_barrier();
    int cur = it & 1;
#pragma unroll
    for (int kk = 0; kk < 2; ++kk) {
      short8 bv[4];
#pragma unroll
      for (int nt = 0; nt < 4; ++nt)
        bv[nt] = *reinterpret_cast<const short8*>(&Bs[cur][bRow[nt] + xq[kk]]);
#pragma unroll
      for (int mt = 0; mt < 8; ++mt) {
        short8 av = *reinterpret_cast<const short8*>(&As[cur][aRow[mt] + xq[kk]]);
#pragma unroll
        for (int nt = 0; nt < 4; ++nt)
          acc[mt][nt] = __builtin_amdgcn_mfma_f32_16x16x32_bf16(av, bv[nt], acc[mt][nt], 0, 0, 0);
      }
    }
    __builtin_amdgcn_s_barrier();
    if (it + 2 < NIT) STAGE2(cur, kBeg + (it + 2) * 64);
  }
#undef STAGE2

  float b2v[4];
#pragma unroll
  for (int nt = 0; nt < 4; ++nt)
    b2v[nt] = (kc == 0) ? b2[e * H + n0 + wn * 64 + nt * 16 + l16] : 0.0f;
#pragma unroll
  for (int mt = 0; mt < 8; ++mt) {
#pragma unroll
    for (int i = 0; i < 4; ++i) {
      int row = wm * 128 + mt * 16 + quad * 4 + i;
      int gr = m0 + row;
      if (gr < n) {
        float wv2 = wgt[e * T + gr];
        int tk = tok[e * T + gr];
        float* orow = out + (size_t)tk * H + n0 + wn * 64 + l16;
#pragma unroll
        for (int nt = 0; nt < 4; ++nt)
          atomicAdd(orow + nt * 16, (acc[mt][nt][i] + b2v[nt]) * wv2);
      }
    }
  }
}

extern "C" void kernel_launch(void* const* d_in, const int* in_sizes, int n_in,
                              void* d_out, int out_size, void* d_ws, size_t ws_size,
                              hipStream_t stream) {
  const float* x  = (const float*)d_in[0];
  const float* Wr = (const float*)d_in[1];
  const float* W1 = (const float*)d_in[2];
  const float* b1 = (const float*)d_in[3];
  const float* W2 = (const float*)d_in[4];
  const float* b2 = (const float*)d_in[5];
  float* out = (float*)d_out;

  char* ws = (char*)d_ws;
  // cnt@0 off@256 tok@4096(128K) wgt@135168(128K) Xb@266240(8M)
  // W1t@8654848(64M) W2t@75763712(64M) Hc@142872576(65M+slack) -> ~201MB total
  int*   cnt = (int*)(ws + 0);
  int*   off = (int*)(ws + 256);
  int*   tok = (int*)(ws + 4096);
  float* wgt = (float*)(ws + 135168);
  u16*   Xb  = (u16*)(ws + 266240);
  u16*   W1t = (u16*)(ws + 8654848);
  u16*   W2t = (u16*)(ws + 75763712);
  u16*   Hc  = (u16*)(ws + 142872576);

  hipMemsetAsync(cnt, 0, 64, stream);
  hipMemsetAsync(out, 0, (size_t)out_size * sizeof(float), stream);

  router_kernel<<<dim3(T / 4), dim3(256), 0, stream>>>(x, Wr, cnt, tok, wgt);
  offsets_kernel<<<dim3(1), dim3(64), 0, stream>>>(cnt, off);
  convert_x_kernel<<<dim3((T * H / 4) / 256), dim3(256), 0, stream>>>(x, Xb);
  transpose_both_kernel<<<dim3(64, 16, 16), dim3(256), 0, stream>>>(W1, W2, W1t, W2t);
  gemm1_kernel<<<dim3(8 * 6 * 16), dim3(512), 0, stream>>>(Xb, W1t, b1, cnt, off, tok, Hc);
  gemm2_kernel<<<dim3(8 * 6 * 4 * KSPLIT2), dim3(512), 0, stream>>>(Hc, W2t, b2, cnt, off, tok, wgt, out);
}

// Round 7
// 666.107 us; speedup vs baseline: 1.0900x; 1.0900x over previous
//
#include <hip/hip_runtime.h>
#include <hip/hip_bf16.h>

#define H 1024
#define F 4096
#define NE 8
#define T 4096

typedef unsigned short u16;
typedef float floatx4 __attribute__((ext_vector_type(4)));
typedef short short8 __attribute__((ext_vector_type(8)));

__device__ __forceinline__ u16 f2bf(float f) {
  union { float f; unsigned int u; } c; c.f = f;
  unsigned int u = c.u;
  return (u16)((u + 0x7fffu + ((u >> 16) & 1u)) >> 16);
}

// async global->LDS, 16B per lane. LDS dest must be uniform base + lane*16.
__device__ __forceinline__ void load16_lds(const u16* g, u16* l) {
  __builtin_amdgcn_global_load_lds(
      (const __attribute__((address_space(1))) unsigned int*)g,
      (__attribute__((address_space(3))) unsigned int*)l, 16, 0, 0);
}

// exact-enough GELU: erf via Abramowitz-Stegun 7.1.26, |err|<1.5e-7 —
// 4 orders below the bf16 quantum Hc is rounded to.
__device__ __forceinline__ float gelu_f(float v) {
  float y = fabsf(v) * 0.70710678118f;
  float t = __builtin_amdgcn_rcpf(fmaf(0.3275911f, y, 1.0f));
  float p = t * fmaf(t, fmaf(t, fmaf(t, fmaf(t, 1.061405429f, -1.453152027f),
                                     1.421413741f), -0.284496736f), 0.254829592f);
  float e = __builtin_amdgcn_exp2f(-y * y * 1.44269504f);
  float erfv = fmaf(-p, e, 1.0f);          // erf(|v|/sqrt2)
  return fmaf(0.5f * fabsf(v), erfv, 0.5f * v);  // 0.5v(1+sign(v)erf)
}

// ---------------- router: one wave per token, fp64 logits ----------------
// tok entry = t | (slot<<12): slot bit lets gemm2 write Y[t][slot] w/o atomics.
__global__ __launch_bounds__(256) void router_kernel(
    const float* __restrict__ x, const float* __restrict__ Wr,
    int* __restrict__ cnt, int* __restrict__ tok, float* __restrict__ wgt) {
  int t = (blockIdx.x * 256 + threadIdx.x) >> 6;
  int lane = threadIdx.x & 63;
  const float* xr = x + (size_t)t * H;
  double p[NE];
#pragma unroll
  for (int e = 0; e < NE; ++e) p[e] = 0.0;
  for (int k = lane; k < H; k += 64) {
    float xv = xr[k];
    const float4* wr4 = reinterpret_cast<const float4*>(Wr + k * NE);
    float4 a = wr4[0], b = wr4[1];
    p[0] += (double)xv * a.x; p[1] += (double)xv * a.y;
    p[2] += (double)xv * a.z; p[3] += (double)xv * a.w;
    p[4] += (double)xv * b.x; p[5] += (double)xv * b.y;
    p[6] += (double)xv * b.z; p[7] += (double)xv * b.w;
  }
#pragma unroll
  for (int e = 0; e < NE; ++e) {
#pragma unroll
    for (int off = 32; off; off >>= 1) p[e] += __shfl_down(p[e], off, 64);
  }
  if (lane == 0) {
    int i0 = 0;
#pragma unroll
    for (int e = 1; e < NE; ++e) if (p[e] > p[i0]) i0 = e;
    int i1 = (i0 == 0) ? 1 : 0;
#pragma unroll
    for (int e = 0; e < NE; ++e) if (e != i0 && p[e] > p[i1]) i1 = e;
    double d = exp(p[i1] - p[i0]);
    float w0 = (float)(1.0 / (1.0 + d));
    float w1 = (float)(d / (1.0 + d));
    int pos0 = atomicAdd(&cnt[i0], 1);
    tok[i0 * T + pos0] = t;            // slot 0
    wgt[i0 * T + pos0] = w0;
    int pos1 = atomicAdd(&cnt[i1], 1);
    tok[i1 * T + pos1] = t | 4096;     // slot 1
    wgt[i1 * T + pos1] = w1;
  }
}

__global__ void offsets_kernel(const int* __restrict__ cnt, int* __restrict__ off) {
  if (threadIdx.x == 0) {
    int s = 0;
#pragma unroll
    for (int e = 0; e < NE; ++e) { off[e] = s; s += cnt[e]; }
    off[NE] = s;
  }
}

// ---------------- x -> bf16 ----------------
__global__ __launch_bounds__(256) void convert_x_kernel(
    const float* __restrict__ x, u16* __restrict__ xb) {
  int i = blockIdx.x * 256 + threadIdx.x;
  float4 v = reinterpret_cast<const float4*>(x)[i];
  ushort4 o;
  o.x = f2bf(v.x); o.y = f2bf(v.y); o.z = f2bf(v.z); o.w = f2bf(v.w);
  reinterpret_cast<ushort4*>(xb)[i] = o;
}

// ---- fused weight transpose: [E][R][C] f32 -> [E][C][R] bf16, both W1,W2 ----
// 16B (short8) stores on the write side; tile stride 76 u16 = 152B keeps the
// 8-row column gathers at <=4-way bank conflict and short8 stores 8B-aligned.
__global__ __launch_bounds__(256) void transpose_both_kernel(
    const float* __restrict__ W1, const float* __restrict__ W2,
    u16* __restrict__ W1t, u16* __restrict__ W2t) {
  __shared__ u16 tile[64][76];
  int z = blockIdx.z;
  int e = z & 7;
  const float* s; u16* d; int R, C, c0, r0;
  if (z < NE) {
    s = W1 + (size_t)e * H * F; d = W1t + (size_t)e * H * F;
    R = H; C = F; c0 = blockIdx.x << 6; r0 = blockIdx.y << 6;
  } else {
    s = W2 + (size_t)e * F * H; d = W2t + (size_t)e * F * H;
    R = F; C = H; c0 = blockIdx.y << 6; r0 = blockIdx.x << 6;
  }
  int t = threadIdx.x;
  int rl = t >> 4, cl = (t & 15) << 2;
#pragma unroll
  for (int i = 0; i < 4; ++i) {
    float4 v = *reinterpret_cast<const float4*>(&s[(size_t)(r0 + rl + i * 16) * C + c0 + cl]);
    ushort4 o; o.x = f2bf(v.x); o.y = f2bf(v.y); o.z = f2bf(v.z); o.w = f2bf(v.w);
    *reinterpret_cast<ushort4*>(&tile[rl + i * 16][cl]) = o;
  }
  __syncthreads();
  int cw = t >> 3, rw = (t & 7) << 3;
#pragma unroll
  for (int i = 0; i < 2; ++i) {
    int c = cw + i * 32;
    short8 o;
#pragma unroll
    for (int j = 0; j < 8; ++j) o[j] = (short)tile[rw + j][c];
    *reinterpret_cast<short8*>(&d[(size_t)(c0 + c) * R + r0 + rw]) = o;
  }
}

// ---------------- GEMM1: Hc = gelu(gather(Xb) @ W1t^T + b1) ----------------
// round-4 verified loop: 2 LDS buffers + depth-2 counted vmcnt(4); chunk-XOR
// LDS swizzle (phys 16B chunk p of row r holds k-chunk p^((r>>1)&3)) -> 0
// bank conflicts. grid (F/128, 32, NE).
__global__ __launch_bounds__(256) void gemm1_kernel(
    const u16* __restrict__ Xb, const u16* __restrict__ W1t,
    const float* __restrict__ b1, const int* __restrict__ cnt,
    const int* __restrict__ off, const int* __restrict__ tok,
    u16* __restrict__ Hc) {
  int e = blockIdx.z;
  int n = cnt[e];
  int m0 = blockIdx.y << 7;
  if (m0 >= n) return;
  int n0 = blockIdx.x << 7;
  int rb = off[e];

  __shared__ alignas(16) u16 As[2][128 * 32];
  __shared__ alignas(16) u16 Bs[2][128 * 32];
  __shared__ int tokS[128];

  int tid = threadIdx.x;
  if (tid < 128) {
    int s = m0 + tid;
    tokS[tid] = (s < n) ? (tok[e * T + s] & 4095) : 0;
  }
  __syncthreads();

  int kchunk = (((tid & 3) ^ ((tid >> 3) & 3))) * 8;
  const u16* W1e = W1t + (size_t)e * F * H;
  const u16* aP0 = Xb + (size_t)tokS[tid >> 2] * H + kchunk;
  const u16* aP1 = Xb + (size_t)tokS[64 + (tid >> 2)] * H + kchunk;
  const u16* bP0 = W1e + (size_t)(n0 + (tid >> 2)) * H + kchunk;
  const u16* bP1 = W1e + (size_t)(n0 + 64 + (tid >> 2)) * H + kchunk;

  int wv = tid >> 6, lane = tid & 63;
  int wm = wv >> 1, wn = wv & 1;
  int quad = lane >> 4, l16 = lane & 15;

  floatx4 acc[4][4];
#pragma unroll
  for (int mt = 0; mt < 4; ++mt)
#pragma unroll
    for (int nt = 0; nt < 4; ++nt) acc[mt][nt] = floatx4{0.f, 0.f, 0.f, 0.f};

  int qa = (quad ^ ((l16 >> 1) & 3)) * 8;
  int aOff[4], bOff[4];
#pragma unroll
  for (int i = 0; i < 4; ++i) {
    aOff[i] = (wm * 64 + i * 16 + l16) * 32 + qa;
    bOff[i] = (wn * 64 + i * 16 + l16) * 32 + qa;
  }

#define STAGE1(buf, kk)                                   \
  do {                                                    \
    load16_lds(aP0 + (kk), &As[buf][tid * 8]);            \
    load16_lds(aP1 + (kk), &As[buf][(tid + 256) * 8]);    \
    load16_lds(bP0 + (kk), &Bs[buf][tid * 8]);            \
    load16_lds(bP1 + (kk), &Bs[buf][(tid + 256) * 8]);    \
  } while (0)

  const int NIT = H / 32;  // 32
  STAGE1(0, 0);
  STAGE1(1, 32);
  for (int it = 0; it < NIT; ++it) {
    if (it >= NIT - 1) asm volatile("s_waitcnt vmcnt(0)" ::: "memory");
    else               asm volatile("s_waitcnt vmcnt(4)" ::: "memory");
    __builtin_amdgcn_s_barrier();
    int cur = it & 1;
    short8 av[4], bv[4];
#pragma unroll
    for (int i = 0; i < 4; ++i) {
      av[i] = *reinterpret_cast<const short8*>(&As[cur][aOff[i]]);
      bv[i] = *reinterpret_cast<const short8*>(&Bs[cur][bOff[i]]);
    }
#pragma unroll
    for (int mt = 0; mt < 4; ++mt)
#pragma unroll
      for (int nt = 0; nt < 4; ++nt)
        acc[mt][nt] = __builtin_amdgcn_mfma_f32_16x16x32_bf16(av[mt], bv[nt], acc[mt][nt], 0, 0, 0);
    __builtin_amdgcn_s_barrier();  // all waves done reading buf cur
    if (it + 2 < NIT) STAGE1(cur, (it + 2) * 32);  // refill freed buffer
  }
#undef STAGE1

  float b1v[4];
#pragma unroll
  for (int nt = 0; nt < 4; ++nt)
    b1v[nt] = b1[e * F + n0 + wn * 64 + nt * 16 + l16];
#pragma unroll
  for (int mt = 0; mt < 4; ++mt) {
#pragma unroll
    for (int i = 0; i < 4; ++i) {
      int row = wm * 64 + mt * 16 + quad * 4 + i;
      int gr = m0 + row;
      if (gr < n) {
        u16* hrow = Hc + (size_t)(rb + gr) * F + n0 + wn * 64 + l16;
#pragma unroll
        for (int nt = 0; nt < 4; ++nt) {
          float v = acc[mt][nt][i] + b1v[nt];
          hrow[nt * 16] = f2bf(gelu_f(v));
        }
      }
    }
  }
}

// ---------------- GEMM2: Y[t][slot] = w * (Hc @ W2t^T + b2) ----------------
// grid 2048 (1D): e = bid&7 (XCD affinity), rem = bid>>3: by = rem&31 fastest
// (W2t panel L2-reuse across m-tiles), bx = rem>>5. No split-K. Epilogue is
// PLAIN STORES into Y[(t*2+slot)*H + col] (slot from tok bit 12) — no atomics,
// no out-memset; combine_kernel sums the two slots per token.
__global__ __launch_bounds__(256) void gemm2_kernel(
    const u16* __restrict__ Hc, const u16* __restrict__ W2t,
    const float* __restrict__ b2, const int* __restrict__ cnt,
    const int* __restrict__ off, const int* __restrict__ tok,
    const float* __restrict__ wgt, float* __restrict__ Yb) {
  int bid = blockIdx.x;
  int e = bid & 7;
  int rem = bid >> 3;                  // [0,256)
  int by = rem & 31;
  int bx = rem >> 5;                   // [0,8)
  int n = cnt[e];
  int m0 = by << 7;
  if (m0 >= n) return;
  int n0 = bx << 7;
  int rb = off[e];

  __shared__ alignas(16) u16 As[2][128 * 32];
  __shared__ alignas(16) u16 Bs[2][128 * 32];

  int tid = threadIdx.x;
  int kchunk = (((tid & 3) ^ ((tid >> 3) & 3))) * 8;
  const u16* W2e = W2t + (size_t)e * F * H;
  const u16* aP0 = Hc + (size_t)(rb + m0 + (tid >> 2)) * F + kchunk;
  const u16* aP1 = Hc + (size_t)(rb + m0 + 64 + (tid >> 2)) * F + kchunk;
  const u16* bP0 = W2e + (size_t)(n0 + (tid >> 2)) * F + kchunk;
  const u16* bP1 = W2e + (size_t)(n0 + 64 + (tid >> 2)) * F + kchunk;

  int wv = tid >> 6, lane = tid & 63;
  int wm = wv >> 1, wn = wv & 1;
  int quad = lane >> 4, l16 = lane & 15;

  floatx4 acc[4][4];
#pragma unroll
  for (int mt = 0; mt < 4; ++mt)
#pragma unroll
    for (int nt = 0; nt < 4; ++nt) acc[mt][nt] = floatx4{0.f, 0.f, 0.f, 0.f};

  int qa = (quad ^ ((l16 >> 1) & 3)) * 8;
  int aOff[4], bOff[4];
#pragma unroll
  for (int i = 0; i < 4; ++i) {
    aOff[i] = (wm * 64 + i * 16 + l16) * 32 + qa;
    bOff[i] = (wn * 64 + i * 16 + l16) * 32 + qa;
  }

#define STAGE2(buf, kk)                                   \
  do {                                                    \
    load16_lds(aP0 + (kk), &As[buf][tid * 8]);            \
    load16_lds(aP1 + (kk), &As[buf][(tid + 256) * 8]);    \
    load16_lds(bP0 + (kk), &Bs[buf][tid * 8]);            \
    load16_lds(bP1 + (kk), &Bs[buf][(tid + 256) * 8]);    \
  } while (0)

  const int NIT = F / 32;  // 128
  STAGE2(0, 0);
  STAGE2(1, 32);
  for (int it = 0; it < NIT; ++it) {
    if (it >= NIT - 1) asm volatile("s_waitcnt vmcnt(0)" ::: "memory");
    else               asm volatile("s_waitcnt vmcnt(4)" ::: "memory");
    __builtin_amdgcn_s_barrier();
    int cur = it & 1;
    short8 av[4], bv[4];
#pragma unroll
    for (int i = 0; i < 4; ++i) {
      av[i] = *reinterpret_cast<const short8*>(&As[cur][aOff[i]]);
      bv[i] = *reinterpret_cast<const short8*>(&Bs[cur][bOff[i]]);
    }
#pragma unroll
    for (int mt = 0; mt < 4; ++mt)
#pragma unroll
      for (int nt = 0; nt < 4; ++nt)
        acc[mt][nt] = __builtin_amdgcn_mfma_f32_16x16x32_bf16(av[mt], bv[nt], acc[mt][nt], 0, 0, 0);
    __builtin_amdgcn_s_barrier();
    if (it + 2 < NIT) STAGE2(cur, (it + 2) * 32);
  }
#undef STAGE2

  float b2v[4];
#pragma unroll
  for (int nt = 0; nt < 4; ++nt)
    b2v[nt] = b2[e * H + n0 + wn * 64 + nt * 16 + l16];
#pragma unroll
  for (int mt = 0; mt < 4; ++mt) {
#pragma unroll
    for (int i = 0; i < 4; ++i) {
      int row = wm * 64 + mt * 16 + quad * 4 + i;
      int gr = m0 + row;
      if (gr < n) {
        float wv2 = wgt[e * T + gr];
        int tk = tok[e * T + gr];
        int t2 = tk & 4095, slot = tk >> 12;
        float* yrow = Yb + ((size_t)t2 * 2 + slot) * H + n0 + wn * 64 + l16;
#pragma unroll
        for (int nt = 0; nt < 4; ++nt)
          yrow[nt * 16] = (acc[mt][nt][i] + b2v[nt]) * wv2;
      }
    }
  }
}

// ---------------- combine: out[t] = Y[t][0] + Y[t][1] ----------------
__global__ __launch_bounds__(256) void combine_kernel(
    const float* __restrict__ Yb, float* __restrict__ out) {
  int i = blockIdx.x * 256 + threadIdx.x;      // float4 index over [T][H]
  int t = i >> 8;                              // H/4 = 256 float4 per row
  int h4 = i & 255;
  const float4* Y4 = reinterpret_cast<const float4*>(Yb);
  float4 a = Y4[((size_t)t * 2) * 256 + h4];
  float4 b = Y4[((size_t)t * 2 + 1) * 256 + h4];
  float4 o; o.x = a.x + b.x; o.y = a.y + b.y; o.z = a.z + b.z; o.w = a.w + b.w;
  reinterpret_cast<float4*>(out)[i] = o;
}

extern "C" void kernel_launch(void* const* d_in, const int* in_sizes, int n_in,
                              void* d_out, int out_size, void* d_ws, size_t ws_size,
                              hipStream_t stream) {
  const float* x  = (const float*)d_in[0];
  const float* Wr = (const float*)d_in[1];
  const float* W1 = (const float*)d_in[2];
  const float* b1 = (const float*)d_in[3];
  const float* W2 = (const float*)d_in[4];
  const float* b2 = (const float*)d_in[5];
  float* out = (float*)d_out;

  char* ws = (char*)d_ws;
  // cnt@0 off@256 tok@4096(128K) wgt@135168(128K) Xb@266240(8M)
  // W1t@8654848(64M) W2t@75763712(64M) Hc@142872576(64M) -> ~201MB total.
  // Yb (32M, [T][2][H] f32) aliases W1t: W1t is dead once gemm1 finishes.
  int*   cnt = (int*)(ws + 0);
  int*   off = (int*)(ws + 256);
  int*   tok = (int*)(ws + 4096);
  float* wgt = (float*)(ws + 135168);
  u16*   Xb  = (u16*)(ws + 266240);
  u16*   W1t = (u16*)(ws + 8654848);
  u16*   W2t = (u16*)(ws + 75763712);
  u16*   Hc  = (u16*)(ws + 142872576);
  float* Yb  = (float*)(ws + 8654848);   // alias of W1t

  hipMemsetAsync(cnt, 0, 64, stream);

  router_kernel<<<dim3(T / 4), dim3(256), 0, stream>>>(x, Wr, cnt, tok, wgt);
  offsets_kernel<<<dim3(1), dim3(64), 0, stream>>>(cnt, off);
  convert_x_kernel<<<dim3((T * H / 4) / 256), dim3(256), 0, stream>>>(x, Xb);
  transpose_both_kernel<<<dim3(64, 16, 16), dim3(256), 0, stream>>>(W1, W2, W1t, W2t);
  gemm1_kernel<<<dim3(F / 128, 32, NE), dim3(256), 0, stream>>>(Xb, W1t, b1, cnt, off, tok, Hc);
  gemm2_kernel<<<dim3(2048), dim3(256), 0, stream>>>(Hc, W2t, b2, cnt, off, tok, wgt, Yb);
  combine_kernel<<<dim3(T * H / 4 / 256), dim3(256), 0, stream>>>(Yb, out);
}

// Round 8
// 665.678 us; speedup vs baseline: 1.0907x; 1.0006x over previous
//
#include <hip/hip_runtime.h>
#include <hip/hip_bf16.h>

#define H 1024
#define F 4096
#define NE 8
#define T 4096

typedef unsigned short u16;
typedef float floatx4 __attribute__((ext_vector_type(4)));
typedef short short8 __attribute__((ext_vector_type(8)));

__device__ __forceinline__ u16 f2bf(float f) {
  union { float f; unsigned int u; } c; c.f = f;
  unsigned int u = c.u;
  return (u16)((u + 0x7fffu + ((u >> 16) & 1u)) >> 16);
}

// async global->LDS, 16B per lane. LDS dest must be uniform base + lane*16.
__device__ __forceinline__ void load16_lds(const u16* g, u16* l) {
  __builtin_amdgcn_global_load_lds(
      (const __attribute__((address_space(1))) unsigned int*)g,
      (__attribute__((address_space(3))) unsigned int*)l, 16, 0, 0);
}

// exact-enough GELU: erf via Abramowitz-Stegun 7.1.26, |err|<1.5e-7.
__device__ __forceinline__ float gelu_f(float v) {
  float y = fabsf(v) * 0.70710678118f;
  float t = __builtin_amdgcn_rcpf(fmaf(0.3275911f, y, 1.0f));
  float p = t * fmaf(t, fmaf(t, fmaf(t, fmaf(t, 1.061405429f, -1.453152027f),
                                     1.421413741f), -0.284496736f), 0.254829592f);
  float e = __builtin_amdgcn_exp2f(-y * y * 1.44269504f);
  float erfv = fmaf(-p, e, 1.0f);
  return fmaf(0.5f * fabsf(v), erfv, 0.5f * v);
}

// ---------------- prep: router ∪ x->bf16 ∪ transpose W1,W2 ----------------
// grid 21504: [0,1024) router, [1024,5120) convert, [5120,21504) transposes.
// All branches independent memory-bound streams -> share HBM pipe, 1 launch.
__global__ __launch_bounds__(256) void prep_kernel(
    const float* __restrict__ x, const float* __restrict__ Wr,
    const float* __restrict__ W1, const float* __restrict__ W2,
    int* __restrict__ cnt, int* __restrict__ tok, float* __restrict__ wgt,
    u16* __restrict__ xb, u16* __restrict__ W1t, u16* __restrict__ W2t) {
  __shared__ u16 tile[64][76];
  int bid = blockIdx.x;
  int tid = threadIdx.x;
  if (bid < 1024) {
    // ---- router: one wave per token, fp64 logits ----
    // tok entry = t | (slot<<12): gemm2 writes Y[t][slot] without atomics.
    int t = (bid * 256 + tid) >> 6;
    int lane = tid & 63;
    const float* xr = x + (size_t)t * H;
    double p[NE];
#pragma unroll
    for (int e = 0; e < NE; ++e) p[e] = 0.0;
    for (int k = lane; k < H; k += 64) {
      float xv = xr[k];
      const float4* wr4 = reinterpret_cast<const float4*>(Wr + k * NE);
      float4 a = wr4[0], b = wr4[1];
      p[0] += (double)xv * a.x; p[1] += (double)xv * a.y;
      p[2] += (double)xv * a.z; p[3] += (double)xv * a.w;
      p[4] += (double)xv * b.x; p[5] += (double)xv * b.y;
      p[6] += (double)xv * b.z; p[7] += (double)xv * b.w;
    }
#pragma unroll
    for (int e = 0; e < NE; ++e) {
#pragma unroll
      for (int off = 32; off; off >>= 1) p[e] += __shfl_down(p[e], off, 64);
    }
    if (lane == 0) {
      int i0 = 0;
#pragma unroll
      for (int e = 1; e < NE; ++e) if (p[e] > p[i0]) i0 = e;
      int i1 = (i0 == 0) ? 1 : 0;
#pragma unroll
      for (int e = 0; e < NE; ++e) if (e != i0 && p[e] > p[i1]) i1 = e;
      double d = exp(p[i1] - p[i0]);
      float w0 = (float)(1.0 / (1.0 + d));
      float w1 = (float)(d / (1.0 + d));
      int pos0 = atomicAdd(&cnt[i0], 1);
      tok[i0 * T + pos0] = t;            // slot 0
      wgt[i0 * T + pos0] = w0;
      int pos1 = atomicAdd(&cnt[i1], 1);
      tok[i1 * T + pos1] = t | 4096;     // slot 1
      wgt[i1 * T + pos1] = w1;
    }
    return;
  }
  if (bid < 5120) {
    // ---- x -> bf16 ----
    int i = (bid - 1024) * 256 + tid;
    float4 v = reinterpret_cast<const float4*>(x)[i];
    ushort4 o;
    o.x = f2bf(v.x); o.y = f2bf(v.y); o.z = f2bf(v.z); o.w = f2bf(v.w);
    reinterpret_cast<ushort4*>(xb)[i] = o;
    return;
  }
  // ---- weight transpose [E][R][C] f32 -> [E][C][R] bf16 (W1 then W2) ----
  // 16B short8 stores on write side; tile stride 76 u16 keeps reads <=4-way.
  int b = bid - 5120;                    // [0,16384)
  const float* s; u16* d; int R, C, c0, r0;
  if (b < 8192) {
    int e = b >> 10, rem = b & 1023;
    s = W1 + (size_t)e * H * F; d = W1t + (size_t)e * H * F;
    R = H; C = F; c0 = (rem & 63) << 6; r0 = (rem >> 6) << 6;
  } else {
    int b2 = b - 8192;
    int e = b2 >> 10, rem = b2 & 1023;
    s = W2 + (size_t)e * F * H; d = W2t + (size_t)e * F * H;
    R = F; C = H; r0 = (rem & 63) << 6; c0 = (rem >> 6) << 6;
  }
  int rl = tid >> 4, cl = (tid & 15) << 2;
#pragma unroll
  for (int i = 0; i < 4; ++i) {
    float4 v = *reinterpret_cast<const float4*>(&s[(size_t)(r0 + rl + i * 16) * C + c0 + cl]);
    ushort4 o; o.x = f2bf(v.x); o.y = f2bf(v.y); o.z = f2bf(v.z); o.w = f2bf(v.w);
    *reinterpret_cast<ushort4*>(&tile[rl + i * 16][cl]) = o;
  }
  __syncthreads();
  int cw = tid >> 3, rw = (tid & 7) << 3;
#pragma unroll
  for (int i = 0; i < 2; ++i) {
    int c = cw + i * 32;
    short8 o;
#pragma unroll
    for (int j = 0; j < 8; ++j) o[j] = (short)tile[rw + j][c];
    *reinterpret_cast<short8*>(&d[(size_t)(c0 + c) * R + r0 + rw]) = o;
  }
}

__global__ void offsets_kernel(const int* __restrict__ cnt, int* __restrict__ off) {
  if (threadIdx.x == 0) {
    int s = 0;
#pragma unroll
    for (int e = 0; e < NE; ++e) { off[e] = s; s += cnt[e]; }
    off[NE] = s;
  }
}

// ============ 128x128 tile, BK=32, 128 thr = 2 waves (64m x 128n each) ======
// Same verified mechanics as round 4/7 (2 LDS buffers, depth-2 counted vmcnt,
// chunk-XOR swizzle: phys 16B chunk p of row r holds k-chunk p^((r>>1)&3)),
// but 2 waves instead of 4: per wave 12 ds_read_b128 feed 32 MFMA (0.375
// reads/MFMA vs 0.5) -> -25% LDS-read traffic, the measured critical pipe.
// 8 loads/stage -> steady-state s_waitcnt vmcnt(8). 4 block-slots/CU.

// ---------------- GEMM1: Hc = gelu(gather(Xb) @ W1t^T + b1) ----------------
__global__ __launch_bounds__(128, 2) void gemm1_kernel(
    const u16* __restrict__ Xb, const u16* __restrict__ W1t,
    const float* __restrict__ b1, const int* __restrict__ cnt,
    const int* __restrict__ off, const int* __restrict__ tok,
    u16* __restrict__ Hc) {
  int e = blockIdx.z;
  int n = cnt[e];
  int m0 = blockIdx.y << 7;
  if (m0 >= n) return;
  int n0 = blockIdx.x << 7;
  int rb = off[e];

  __shared__ alignas(16) u16 As[2][128 * 32];
  __shared__ alignas(16) u16 Bs[2][128 * 32];
  __shared__ int tokS[128];

  int tid = threadIdx.x;
  {
    int s = m0 + tid;
    tokS[tid] = (s < n) ? (tok[e * T + s] & 4095) : 0;
  }
  __syncthreads();

  // staging: 4 chunks/thread per operand; chunk c = tid + s*128: row r=c>>2,
  // phys slot p=c&3; global source k-chunk = p^((r>>1)&3) (pre-swizzled).
  const u16* W1e = W1t + (size_t)e * F * H;
  const u16* aP[4]; const u16* bP[4];
#pragma unroll
  for (int s = 0; s < 4; ++s) {
    int c = tid + s * 128;
    int r = c >> 2, p = c & 3;
    int kcc = (p ^ ((r >> 1) & 3)) * 8;
    aP[s] = Xb + (size_t)tokS[r] * H + kcc;
    bP[s] = W1e + (size_t)(n0 + r) * H + kcc;
  }

  int wv = tid >> 6, lane = tid & 63;
  int quad = lane >> 4, l16 = lane & 15;

  floatx4 acc[4][8];
#pragma unroll
  for (int mt = 0; mt < 4; ++mt)
#pragma unroll
    for (int nt = 0; nt < 8; ++nt) acc[mt][nt] = floatx4{0.f, 0.f, 0.f, 0.f};

  int qa = (quad ^ ((l16 >> 1) & 3)) * 8;
  int aOff[4], bOff[8];
#pragma unroll
  for (int i = 0; i < 4; ++i) aOff[i] = (wv * 64 + i * 16 + l16) * 32 + qa;
#pragma unroll
  for (int i = 0; i < 8; ++i) bOff[i] = (i * 16 + l16) * 32 + qa;

#define STAGE1(buf, kk)                                              \
  do {                                                               \
    _Pragma("unroll")                                                \
    for (int s = 0; s < 4; ++s) {                                    \
      load16_lds(aP[s] + (kk), &As[buf][(tid + s * 128) * 8]);       \
      load16_lds(bP[s] + (kk), &Bs[buf][(tid + s * 128) * 8]);       \
    }                                                                \
  } while (0)

  const int NIT = H / 32;  // 32
  STAGE1(0, 0);
  STAGE1(1, 32);
  for (int it = 0; it < NIT; ++it) {
    if (it >= NIT - 1) asm volatile("s_waitcnt vmcnt(0)" ::: "memory");
    else               asm volatile("s_waitcnt vmcnt(8)" ::: "memory");
    __builtin_amdgcn_s_barrier();
    int cur = it & 1;
    short8 bv[8];
#pragma unroll
    for (int i = 0; i < 8; ++i)
      bv[i] = *reinterpret_cast<const short8*>(&Bs[cur][bOff[i]]);
#pragma unroll
    for (int mt = 0; mt < 4; ++mt) {
      short8 av = *reinterpret_cast<const short8*>(&As[cur][aOff[mt]]);
#pragma unroll
      for (int nt = 0; nt < 8; ++nt)
        acc[mt][nt] = __builtin_amdgcn_mfma_f32_16x16x32_bf16(av, bv[nt], acc[mt][nt], 0, 0, 0);
    }
    __builtin_amdgcn_s_barrier();  // all waves done reading buf cur
    if (it + 2 < NIT) STAGE1(cur, (it + 2) * 32);
  }
#undef STAGE1

  float b1v[8];
#pragma unroll
  for (int nt = 0; nt < 8; ++nt)
    b1v[nt] = b1[e * F + n0 + nt * 16 + l16];
#pragma unroll
  for (int mt = 0; mt < 4; ++mt) {
#pragma unroll
    for (int i = 0; i < 4; ++i) {
      int row = wv * 64 + mt * 16 + quad * 4 + i;
      int gr = m0 + row;
      if (gr < n) {
        u16* hrow = Hc + (size_t)(rb + gr) * F + n0 + l16;
#pragma unroll
        for (int nt = 0; nt < 8; ++nt) {
          float v = acc[mt][nt][i] + b1v[nt];
          hrow[nt * 16] = f2bf(gelu_f(v));
        }
      }
    }
  }
}

// ---------------- GEMM2: Y[t][slot] = w * (Hc @ W2t^T + b2) ----------------
// grid 2048 (1D): e = bid&7 (XCD affinity), rem = bid>>3: by = rem&31 fastest
// (W2t panel L2-reuse), bx = rem>>5. Plain stores into Y[(t*2+slot)*H+col].
__global__ __launch_bounds__(128, 2) void gemm2_kernel(
    const u16* __restrict__ Hc, const u16* __restrict__ W2t,
    const float* __restrict__ b2, const int* __restrict__ cnt,
    const int* __restrict__ off, const int* __restrict__ tok,
    const float* __restrict__ wgt, float* __restrict__ Yb) {
  int bid = blockIdx.x;
  int e = bid & 7;
  int rem = bid >> 3;                  // [0,256)
  int by = rem & 31;
  int bx = rem >> 5;                   // [0,8)
  int n = cnt[e];
  int m0 = by << 7;
  if (m0 >= n) return;
  int n0 = bx << 7;
  int rb = off[e];

  __shared__ alignas(16) u16 As[2][128 * 32];
  __shared__ alignas(16) u16 Bs[2][128 * 32];

  int tid = threadIdx.x;
  const u16* W2e = W2t + (size_t)e * F * H;
  const u16* aP[4]; const u16* bP[4];
#pragma unroll
  for (int s = 0; s < 4; ++s) {
    int c = tid + s * 128;
    int r = c >> 2, p = c & 3;
    int kcc = (p ^ ((r >> 1) & 3)) * 8;
    aP[s] = Hc + (size_t)(rb + m0 + r) * F + kcc;
    bP[s] = W2e + (size_t)(n0 + r) * F + kcc;
  }

  int wv = tid >> 6, lane = tid & 63;
  int quad = lane >> 4, l16 = lane & 15;

  floatx4 acc[4][8];
#pragma unroll
  for (int mt = 0; mt < 4; ++mt)
#pragma unroll
    for (int nt = 0; nt < 8; ++nt) acc[mt][nt] = floatx4{0.f, 0.f, 0.f, 0.f};

  int qa = (quad ^ ((l16 >> 1) & 3)) * 8;
  int aOff[4], bOff[8];
#pragma unroll
  for (int i = 0; i < 4; ++i) aOff[i] = (wv * 64 + i * 16 + l16) * 32 + qa;
#pragma unroll
  for (int i = 0; i < 8; ++i) bOff[i] = (i * 16 + l16) * 32 + qa;

#define STAGE2(buf, kk)                                              \
  do {                                                               \
    _Pragma("unroll")                                                \
    for (int s = 0; s < 4; ++s) {                                    \
      load16_lds(aP[s] + (kk), &As[buf][(tid + s * 128) * 8]);       \
      load16_lds(bP[s] + (kk), &Bs[buf][(tid + s * 128) * 8]);       \
    }                                                                \
  } while (0)

  const int NIT = F / 32;  // 128
  STAGE2(0, 0);
  STAGE2(1, 32);
  for (int it = 0; it < NIT; ++it) {
    if (it >= NIT - 1) asm volatile("s_waitcnt vmcnt(0)" ::: "memory");
    else               asm volatile("s_waitcnt vmcnt(8)" ::: "memory");
    __builtin_amdgcn_s_barrier();
    int cur = it & 1;
    short8 bv[8];
#pragma unroll
    for (int i = 0; i < 8; ++i)
      bv[i] = *reinterpret_cast<const short8*>(&Bs[cur][bOff[i]]);
#pragma unroll
    for (int mt = 0; mt < 4; ++mt) {
      short8 av = *reinterpret_cast<const short8*>(&As[cur][aOff[mt]]);
#pragma unroll
      for (int nt = 0; nt < 8; ++nt)
        acc[mt][nt] = __builtin_amdgcn_mfma_f32_16x16x32_bf16(av, bv[nt], acc[mt][nt], 0, 0, 0);
    }
    __builtin_amdgcn_s_barrier();
    if (it + 2 < NIT) STAGE2(cur, (it + 2) * 32);
  }
#undef STAGE2

  float b2v[8];
#pragma unroll
  for (int nt = 0; nt < 8; ++nt)
    b2v[nt] = b2[e * H + n0 + nt * 16 + l16];
#pragma unroll
  for (int mt = 0; mt < 4; ++mt) {
#pragma unroll
    for (int i = 0; i < 4; ++i) {
      int row = wv * 64 + mt * 16 + quad * 4 + i;
      int gr = m0 + row;
      if (gr < n) {
        float wv2 = wgt[e * T + gr];
        int tk = tok[e * T + gr];
        int t2 = tk & 4095, slot = tk >> 12;
        float* yrow = Yb + ((size_t)t2 * 2 + slot) * H + n0 + l16;
#pragma unroll
        for (int nt = 0; nt < 8; ++nt)
          yrow[nt * 16] = (acc[mt][nt][i] + b2v[nt]) * wv2;
      }
    }
  }
}

// ---------------- combine: out[t] = Y[t][0] + Y[t][1] ----------------
__global__ __launch_bounds__(256) void combine_kernel(
    const float* __restrict__ Yb, float* __restrict__ out) {
  int i = blockIdx.x * 256 + threadIdx.x;      // float4 index over [T][H]
  int t = i >> 8;                              // H/4 = 256 float4 per row
  int h4 = i & 255;
  const float4* Y4 = reinterpret_cast<const float4*>(Yb);
  float4 a = Y4[((size_t)t * 2) * 256 + h4];
  float4 b = Y4[((size_t)t * 2 + 1) * 256 + h4];
  float4 o; o.x = a.x + b.x; o.y = a.y + b.y; o.z = a.z + b.z; o.w = a.w + b.w;
  reinterpret_cast<float4*>(out)[i] = o;
}

extern "C" void kernel_launch(void* const* d_in, const int* in_sizes, int n_in,
                              void* d_out, int out_size, void* d_ws, size_t ws_size,
                              hipStream_t stream) {
  const float* x  = (const float*)d_in[0];
  const float* Wr = (const float*)d_in[1];
  const float* W1 = (const float*)d_in[2];
  const float* b1 = (const float*)d_in[3];
  const float* W2 = (const float*)d_in[4];
  const float* b2 = (const float*)d_in[5];
  float* out = (float*)d_out;

  char* ws = (char*)d_ws;
  // cnt@0 off@256 tok@4096(128K) wgt@135168(128K) Xb@266240(8M)
  // W1t@8654848(64M) W2t@75763712(64M) Hc@142872576(64M) -> ~201MB total.
  // Yb (32M, [T][2][H] f32) aliases W1t: W1t is dead once gemm1 finishes.
  int*   cnt = (int*)(ws + 0);
  int*   off = (int*)(ws + 256);
  int*   tok = (int*)(ws + 4096);
  float* wgt = (float*)(ws + 135168);
  u16*   Xb  = (u16*)(ws + 266240);
  u16*   W1t = (u16*)(ws + 8654848);
  u16*   W2t = (u16*)(ws + 75763712);
  u16*   Hc  = (u16*)(ws + 142872576);
  float* Yb  = (float*)(ws + 8654848);   // alias of W1t

  hipMemsetAsync(cnt, 0, 64, stream);

  prep_kernel<<<dim3(21504), dim3(256), 0, stream>>>(x, Wr, W1, W2, cnt, tok, wgt, Xb, W1t, W2t);
  offsets_kernel<<<dim3(1), dim3(64), 0, stream>>>(cnt, off);
  gemm1_kernel<<<dim3(F / 128, 32, NE), dim3(128), 0, stream>>>(Xb, W1t, b1, cnt, off, tok, Hc);
  gemm2_kernel<<<dim3(2048), dim3(128), 0, stream>>>(Hc, W2t, b2, cnt, off, tok, wgt, Yb);
  combine_kernel<<<dim3(T * H / 4 / 256), dim3(256), 0, stream>>>(Yb, out);
}

// Round 9
// 644.301 us; speedup vs baseline: 1.1269x; 1.0332x over previous
//
#include <hip/hip_runtime.h>
#include <hip/hip_bf16.h>

#define H 1024
#define F 4096
#define NE 8
#define T 4096

typedef unsigned short u16;
typedef float floatx4 __attribute__((ext_vector_type(4)));
typedef short short8 __attribute__((ext_vector_type(8)));

__device__ __forceinline__ u16 f2bf(float f) {
  union { float f; unsigned int u; } c; c.f = f;
  unsigned int u = c.u;
  return (u16)((u + 0x7fffu + ((u >> 16) & 1u)) >> 16);
}

// async global->LDS, 16B per lane. LDS dest must be uniform base + lane*16.
__device__ __forceinline__ void load16_lds(const u16* g, u16* l) {
  __builtin_amdgcn_global_load_lds(
      (const __attribute__((address_space(1))) unsigned int*)g,
      (__attribute__((address_space(3))) unsigned int*)l, 16, 0, 0);
}

// exact-enough GELU: erf via Abramowitz-Stegun 7.1.26, |err|<1.5e-7.
__device__ __forceinline__ float gelu_f(float v) {
  float y = fabsf(v) * 0.70710678118f;
  float t = __builtin_amdgcn_rcpf(fmaf(0.3275911f, y, 1.0f));
  float p = t * fmaf(t, fmaf(t, fmaf(t, fmaf(t, 1.061405429f, -1.453152027f),
                                     1.421413741f), -0.284496736f), 0.254829592f);
  float e = __builtin_amdgcn_exp2f(-y * y * 1.44269504f);
  float erfv = fmaf(-p, e, 1.0f);
  return fmaf(0.5f * fabsf(v), erfv, 0.5f * v);
}

// ---------------- prep: router ∪ x->bf16 ∪ transpose W1,W2 ----------------
// grid 21504: [0,1024) router, [1024,5120) convert, [5120,21504) transposes.
// Transpose body = round-4 tile (ushort4 8B stores, [64][72] pad) — the
// round-7 short8 rewrite is reverted to deconfound it from the fusion.
__global__ __launch_bounds__(256) void prep_kernel(
    const float* __restrict__ x, const float* __restrict__ Wr,
    const float* __restrict__ W1, const float* __restrict__ W2,
    int* __restrict__ cnt, int* __restrict__ tok, float* __restrict__ wgt,
    u16* __restrict__ xb, u16* __restrict__ W1t, u16* __restrict__ W2t) {
  __shared__ u16 tile[64][72];
  int bid = blockIdx.x;
  int tid = threadIdx.x;
  if (bid < 1024) {
    // ---- router: one wave per token, fp64 logits ----
    // tok entry = t | (slot<<12): gemm2 writes Y[t][slot] without atomics.
    int t = (bid * 256 + tid) >> 6;
    int lane = tid & 63;
    const float* xr = x + (size_t)t * H;
    double p[NE];
#pragma unroll
    for (int e = 0; e < NE; ++e) p[e] = 0.0;
    for (int k = lane; k < H; k += 64) {
      float xv = xr[k];
      const float4* wr4 = reinterpret_cast<const float4*>(Wr + k * NE);
      float4 a = wr4[0], b = wr4[1];
      p[0] += (double)xv * a.x; p[1] += (double)xv * a.y;
      p[2] += (double)xv * a.z; p[3] += (double)xv * a.w;
      p[4] += (double)xv * b.x; p[5] += (double)xv * b.y;
      p[6] += (double)xv * b.z; p[7] += (double)xv * b.w;
    }
#pragma unroll
    for (int e = 0; e < NE; ++e) {
#pragma unroll
      for (int off = 32; off; off >>= 1) p[e] += __shfl_down(p[e], off, 64);
    }
    if (lane == 0) {
      int i0 = 0;
#pragma unroll
      for (int e = 1; e < NE; ++e) if (p[e] > p[i0]) i0 = e;
      int i1 = (i0 == 0) ? 1 : 0;
#pragma unroll
      for (int e = 0; e < NE; ++e) if (e != i0 && p[e] > p[i1]) i1 = e;
      double d = exp(p[i1] - p[i0]);
      float w0 = (float)(1.0 / (1.0 + d));
      float w1 = (float)(d / (1.0 + d));
      int pos0 = atomicAdd(&cnt[i0], 1);
      tok[i0 * T + pos0] = t;            // slot 0
      wgt[i0 * T + pos0] = w0;
      int pos1 = atomicAdd(&cnt[i1], 1);
      tok[i1 * T + pos1] = t | 4096;     // slot 1
      wgt[i1 * T + pos1] = w1;
    }
    return;
  }
  if (bid < 5120) {
    // ---- x -> bf16 ----
    int i = (bid - 1024) * 256 + tid;
    float4 v = reinterpret_cast<const float4*>(x)[i];
    ushort4 o;
    o.x = f2bf(v.x); o.y = f2bf(v.y); o.z = f2bf(v.z); o.w = f2bf(v.w);
    reinterpret_cast<ushort4*>(xb)[i] = o;
    return;
  }
  // ---- weight transpose [E][R][C] f32 -> [E][C][R] bf16 (W1 then W2) ----
  int b = bid - 5120;                    // [0,16384)
  const float* s; u16* d; int R, C, c0, r0;
  if (b < 8192) {
    int e = b >> 10, rem = b & 1023;
    s = W1 + (size_t)e * H * F; d = W1t + (size_t)e * H * F;
    R = H; C = F; c0 = (rem & 63) << 6; r0 = (rem >> 6) << 6;
  } else {
    int b2 = b - 8192;
    int e = b2 >> 10, rem = b2 & 1023;
    s = W2 + (size_t)e * F * H; d = W2t + (size_t)e * F * H;
    R = F; C = H; r0 = (rem & 63) << 6; c0 = (rem >> 6) << 6;
  }
  int rl = tid >> 4, cl = (tid & 15) << 2;
#pragma unroll
  for (int i = 0; i < 4; ++i) {
    float4 v = *reinterpret_cast<const float4*>(&s[(size_t)(r0 + rl + i * 16) * C + c0 + cl]);
    ushort4 o; o.x = f2bf(v.x); o.y = f2bf(v.y); o.z = f2bf(v.z); o.w = f2bf(v.w);
    *reinterpret_cast<ushort4*>(&tile[rl + i * 16][cl]) = o;
  }
  __syncthreads();
  int cl2 = tid >> 4, rl2 = (tid & 15) << 2;
#pragma unroll
  for (int i = 0; i < 4; ++i) {
    ushort4 o;
    o.x = tile[rl2 + 0][cl2 + i * 16];
    o.y = tile[rl2 + 1][cl2 + i * 16];
    o.z = tile[rl2 + 2][cl2 + i * 16];
    o.w = tile[rl2 + 3][cl2 + i * 16];
    *reinterpret_cast<ushort4*>(&d[(size_t)(c0 + cl2 + i * 16) * R + r0 + rl2]) = o;
  }
}

__global__ void offsets_kernel(const int* __restrict__ cnt, int* __restrict__ off) {
  if (threadIdx.x == 0) {
    int s = 0;
#pragma unroll
    for (int e = 0; e < NE; ++e) { off[e] = s; s += cnt[e]; }
    off[NE] = s;
  }
}

// ======== round-7 GEMM bodies: 128x128 tile, 256 thr (2x2 waves of 64x64),
// 2 LDS buffers + depth-2 counted vmcnt(4), chunk-XOR swizzle (phys 16B chunk
// p of row r holds k-chunk p^((r>>1)&3)) -> 0 bank conflicts (measured). ====

// ---------------- GEMM1: Hc = gelu(gather(Xb) @ W1t^T + b1) ----------------
__global__ __launch_bounds__(256) void gemm1_kernel(
    const u16* __restrict__ Xb, const u16* __restrict__ W1t,
    const float* __restrict__ b1, const int* __restrict__ cnt,
    const int* __restrict__ off, const int* __restrict__ tok,
    u16* __restrict__ Hc) {
  int e = blockIdx.z;
  int n = cnt[e];
  int m0 = blockIdx.y << 7;
  if (m0 >= n) return;
  int n0 = blockIdx.x << 7;
  int rb = off[e];

  __shared__ alignas(16) u16 As[2][128 * 32];
  __shared__ alignas(16) u16 Bs[2][128 * 32];
  __shared__ int tokS[128];

  int tid = threadIdx.x;
  if (tid < 128) {
    int s = m0 + tid;
    tokS[tid] = (s < n) ? (tok[e * T + s] & 4095) : 0;
  }
  __syncthreads();

  int kchunk = (((tid & 3) ^ ((tid >> 3) & 3))) * 8;
  const u16* W1e = W1t + (size_t)e * F * H;
  const u16* aP0 = Xb + (size_t)tokS[tid >> 2] * H + kchunk;
  const u16* aP1 = Xb + (size_t)tokS[64 + (tid >> 2)] * H + kchunk;
  const u16* bP0 = W1e + (size_t)(n0 + (tid >> 2)) * H + kchunk;
  const u16* bP1 = W1e + (size_t)(n0 + 64 + (tid >> 2)) * H + kchunk;

  int wv = tid >> 6, lane = tid & 63;
  int wm = wv >> 1, wn = wv & 1;
  int quad = lane >> 4, l16 = lane & 15;

  floatx4 acc[4][4];
#pragma unroll
  for (int mt = 0; mt < 4; ++mt)
#pragma unroll
    for (int nt = 0; nt < 4; ++nt) acc[mt][nt] = floatx4{0.f, 0.f, 0.f, 0.f};

  int qa = (quad ^ ((l16 >> 1) & 3)) * 8;
  int aOff[4], bOff[4];
#pragma unroll
  for (int i = 0; i < 4; ++i) {
    aOff[i] = (wm * 64 + i * 16 + l16) * 32 + qa;
    bOff[i] = (wn * 64 + i * 16 + l16) * 32 + qa;
  }

#define STAGE1(buf, kk)                                   \
  do {                                                    \
    load16_lds(aP0 + (kk), &As[buf][tid * 8]);            \
    load16_lds(aP1 + (kk), &As[buf][(tid + 256) * 8]);    \
    load16_lds(bP0 + (kk), &Bs[buf][tid * 8]);            \
    load16_lds(bP1 + (kk), &Bs[buf][(tid + 256) * 8]);    \
  } while (0)

  const int NIT = H / 32;  // 32
  STAGE1(0, 0);
  STAGE1(1, 32);
  for (int it = 0; it < NIT; ++it) {
    if (it >= NIT - 1) asm volatile("s_waitcnt vmcnt(0)" ::: "memory");
    else               asm volatile("s_waitcnt vmcnt(4)" ::: "memory");
    __builtin_amdgcn_s_barrier();
    int cur = it & 1;
    short8 av[4], bv[4];
#pragma unroll
    for (int i = 0; i < 4; ++i) {
      av[i] = *reinterpret_cast<const short8*>(&As[cur][aOff[i]]);
      bv[i] = *reinterpret_cast<const short8*>(&Bs[cur][bOff[i]]);
    }
#pragma unroll
    for (int mt = 0; mt < 4; ++mt)
#pragma unroll
      for (int nt = 0; nt < 4; ++nt)
        acc[mt][nt] = __builtin_amdgcn_mfma_f32_16x16x32_bf16(av[mt], bv[nt], acc[mt][nt], 0, 0, 0);
    __builtin_amdgcn_s_barrier();  // all waves done reading buf cur
    if (it + 2 < NIT) STAGE1(cur, (it + 2) * 32);  // refill freed buffer
  }
#undef STAGE1

  float b1v[4];
#pragma unroll
  for (int nt = 0; nt < 4; ++nt)
    b1v[nt] = b1[e * F + n0 + wn * 64 + nt * 16 + l16];
#pragma unroll
  for (int mt = 0; mt < 4; ++mt) {
#pragma unroll
    for (int i = 0; i < 4; ++i) {
      int row = wm * 64 + mt * 16 + quad * 4 + i;
      int gr = m0 + row;
      if (gr < n) {
        u16* hrow = Hc + (size_t)(rb + gr) * F + n0 + wn * 64 + l16;
#pragma unroll
        for (int nt = 0; nt < 4; ++nt) {
          float v = acc[mt][nt][i] + b1v[nt];
          hrow[nt * 16] = f2bf(gelu_f(v));
        }
      }
    }
  }
}

// ---------------- GEMM2: Y[t][slot] = w * (Hc @ W2t^T + b2) ----------------
// grid 2048 (1D): e = bid&7 (XCD affinity), rem = bid>>3: by = rem&31 fastest
// (W2t panel L2-reuse), bx = rem>>5. Plain stores into Y[(t*2+slot)*H+col].
__global__ __launch_bounds__(256) void gemm2_kernel(
    const u16* __restrict__ Hc, const u16* __restrict__ W2t,
    const float* __restrict__ b2, const int* __restrict__ cnt,
    const int* __restrict__ off, const int* __restrict__ tok,
    const float* __restrict__ wgt, float* __restrict__ Yb) {
  int bid = blockIdx.x;
  int e = bid & 7;
  int rem = bid >> 3;                  // [0,256)
  int by = rem & 31;
  int bx = rem >> 5;                   // [0,8)
  int n = cnt[e];
  int m0 = by << 7;
  if (m0 >= n) return;
  int n0 = bx << 7;
  int rb = off[e];

  __shared__ alignas(16) u16 As[2][128 * 32];
  __shared__ alignas(16) u16 Bs[2][128 * 32];

  int tid = threadIdx.x;
  int kchunk = (((tid & 3) ^ ((tid >> 3) & 3))) * 8;
  const u16* W2e = W2t + (size_t)e * F * H;
  const u16* aP0 = Hc + (size_t)(rb + m0 + (tid >> 2)) * F + kchunk;
  const u16* aP1 = Hc + (size_t)(rb + m0 + 64 + (tid >> 2)) * F + kchunk;
  const u16* bP0 = W2e + (size_t)(n0 + (tid >> 2)) * F + kchunk;
  const u16* bP1 = W2e + (size_t)(n0 + 64 + (tid >> 2)) * F + kchunk;

  int wv = tid >> 6, lane = tid & 63;
  int wm = wv >> 1, wn = wv & 1;
  int quad = lane >> 4, l16 = lane & 15;

  floatx4 acc[4][4];
#pragma unroll
  for (int mt = 0; mt < 4; ++mt)
#pragma unroll
    for (int nt = 0; nt < 4; ++nt) acc[mt][nt] = floatx4{0.f, 0.f, 0.f, 0.f};

  int qa = (quad ^ ((l16 >> 1) & 3)) * 8;
  int aOff[4], bOff[4];
#pragma unroll
  for (int i = 0; i < 4; ++i) {
    aOff[i] = (wm * 64 + i * 16 + l16) * 32 + qa;
    bOff[i] = (wn * 64 + i * 16 + l16) * 32 + qa;
  }

#define STAGE2(buf, kk)                                   \
  do {                                                    \
    load16_lds(aP0 + (kk), &As[buf][tid * 8]);            \
    load16_lds(aP1 + (kk), &As[buf][(tid + 256) * 8]);    \
    load16_lds(bP0 + (kk), &Bs[buf][tid * 8]);            \
    load16_lds(bP1 + (kk), &Bs[buf][(tid + 256) * 8]);    \
  } while (0)

  const int NIT = F / 32;  // 128
  STAGE2(0, 0);
  STAGE2(1, 32);
  for (int it = 0; it < NIT; ++it) {
    if (it >= NIT - 1) asm volatile("s_waitcnt vmcnt(0)" ::: "memory");
    else               asm volatile("s_waitcnt vmcnt(4)" ::: "memory");
    __builtin_amdgcn_s_barrier();
    int cur = it & 1;
    short8 av[4], bv[4];
#pragma unroll
    for (int i = 0; i < 4; ++i) {
      av[i] = *reinterpret_cast<const short8*>(&As[cur][aOff[i]]);
      bv[i] = *reinterpret_cast<const short8*>(&Bs[cur][bOff[i]]);
    }
#pragma unroll
    for (int mt = 0; mt < 4; ++mt)
#pragma unroll
      for (int nt = 0; nt < 4; ++nt)
        acc[mt][nt] = __builtin_amdgcn_mfma_f32_16x16x32_bf16(av[mt], bv[nt], acc[mt][nt], 0, 0, 0);
    __builtin_amdgcn_s_barrier();
    if (it + 2 < NIT) STAGE2(cur, (it + 2) * 32);
  }
#undef STAGE2

  float b2v[4];
#pragma unroll
  for (int nt = 0; nt < 4; ++nt)
    b2v[nt] = b2[e * H + n0 + wn * 64 + nt * 16 + l16];
#pragma unroll
  for (int mt = 0; mt < 4; ++mt) {
#pragma unroll
    for (int i = 0; i < 4; ++i) {
      int row = wm * 64 + mt * 16 + quad * 4 + i;
      int gr = m0 + row;
      if (gr < n) {
        float wv2 = wgt[e * T + gr];
        int tk = tok[e * T + gr];
        int t2 = tk & 4095, slot = tk >> 12;
        float* yrow = Yb + ((size_t)t2 * 2 + slot) * H + n0 + wn * 64 + l16;
#pragma unroll
        for (int nt = 0; nt < 4; ++nt)
          yrow[nt * 16] = (acc[mt][nt][i] + b2v[nt]) * wv2;
      }
    }
  }
}

// ---------------- combine: out[t] = Y[t][0] + Y[t][1] ----------------
__global__ __launch_bounds__(256) void combine_kernel(
    const float* __restrict__ Yb, float* __restrict__ out) {
  int i = blockIdx.x * 256 + threadIdx.x;      // float4 index over [T][H]
  int t = i >> 8;                              // H/4 = 256 float4 per row
  int h4 = i & 255;
  const float4* Y4 = reinterpret_cast<const float4*>(Yb);
  float4 a = Y4[((size_t)t * 2) * 256 + h4];
  float4 b = Y4[((size_t)t * 2 + 1) * 256 + h4];
  float4 o; o.x = a.x + b.x; o.y = a.y + b.y; o.z = a.z + b.z; o.w = a.w + b.w;
  reinterpret_cast<float4*>(out)[i] = o;
}

extern "C" void kernel_launch(void* const* d_in, const int* in_sizes, int n_in,
                              void* d_out, int out_size, void* d_ws, size_t ws_size,
                              hipStream_t stream) {
  const float* x  = (const float*)d_in[0];
  const float* Wr = (const float*)d_in[1];
  const float* W1 = (const float*)d_in[2];
  const float* b1 = (const float*)d_in[3];
  const float* W2 = (const float*)d_in[4];
  const float* b2 = (const float*)d_in[5];
  float* out = (float*)d_out;

  char* ws = (char*)d_ws;
  // cnt@0 off@256 tok@4096(128K) wgt@135168(128K) Xb@266240(8M)
  // W1t@8654848(64M) W2t@75763712(64M) Hc@142872576(64M) -> ~201MB total.
  // Yb (32M, [T][2][H] f32) aliases W1t: W1t is dead once gemm1 finishes.
  int*   cnt = (int*)(ws + 0);
  int*   off = (int*)(ws + 256);
  int*   tok = (int*)(ws + 4096);
  float* wgt = (float*)(ws + 135168);
  u16*   Xb  = (u16*)(ws + 266240);
  u16*   W1t = (u16*)(ws + 8654848);
  u16*   W2t = (u16*)(ws + 75763712);
  u16*   Hc  = (u16*)(ws + 142872576);
  float* Yb  = (float*)(ws + 8654848);   // alias of W1t

  hipMemsetAsync(cnt, 0, 64, stream);

  prep_kernel<<<dim3(21504), dim3(256), 0, stream>>>(x, Wr, W1, W2, cnt, tok, wgt, Xb, W1t, W2t);
  offsets_kernel<<<dim3(1), dim3(64), 0, stream>>>(cnt, off);
  gemm1_kernel<<<dim3(F / 128, 32, NE), dim3(256), 0, stream>>>(Xb, W1t, b1, cnt, off, tok, Hc);
  gemm2_kernel<<<dim3(2048), dim3(256), 0, stream>>>(Hc, W2t, b2, cnt, off, tok, wgt, Yb);
  combine_kernel<<<dim3(T * H / 4 / 256), dim3(256), 0, stream>>>(Yb, out);
}